// Round 8
// baseline (6833.820 us; speedup 1.0000x reference)
//
#include <hip/hip_runtime.h>
#include <math.h>

#define T_STEPS 64
#define BB 64
#define LL 2048
#define EE 128
#define HH 256
#define NCHUNK 32
#define LCHUNK (LL / NCHUNK) /* 64 */

__device__ __forceinline__ float fexp(float x) {
    return __builtin_amdgcn_exp2f(x * 1.44269504088896340736f);
}
__device__ __forceinline__ float fsig(float x) {
    return __builtin_amdgcn_rcpf(1.f + __builtin_amdgcn_exp2f(-1.44269504088896340736f * x));
}
__device__ __forceinline__ float ftanh(float x) {
    float xc = fminf(fmaxf(x, -20.f), 20.f);
    float p = __builtin_amdgcn_exp2f(2.885390081777926814f * xc); // e^{2x}
    return (p - 1.f) * __builtin_amdgcn_rcpf(p + 1.f);
}
__device__ __forceinline__ unsigned int bfr(float x) {
    unsigned int u = __float_as_uint(x);
    return (u + 0x7FFFu + ((u >> 16) & 1u)) >> 16;
}
__device__ __forceinline__ void bf8x(const uint4 q, float* f) {
    f[0] = __uint_as_float(q.x << 16); f[1] = __uint_as_float(q.x & 0xFFFF0000u);
    f[2] = __uint_as_float(q.y << 16); f[3] = __uint_as_float(q.y & 0xFFFF0000u);
    f[4] = __uint_as_float(q.z << 16); f[5] = __uint_as_float(q.z & 0xFFFF0000u);
    f[6] = __uint_as_float(q.w << 16); f[7] = __uint_as_float(q.w & 0xFFFF0000u);
}
__device__ __forceinline__ void load8(const float* p, float* d) {
    float4 a = *(const float4*)p, b = *(const float4*)(p + 4);
    d[0]=a.x; d[1]=a.y; d[2]=a.z; d[3]=a.w; d[4]=b.x; d[5]=b.y; d[6]=b.z; d[7]=b.w;
}

// ---------------------------------------------------------------------------
// K0: one-time fp32 -> bf16 conversion of enc (RNE).
// ---------------------------------------------------------------------------
__global__ __launch_bounds__(256) void conv_kernel(
    const float4* __restrict__ enc, uint4* __restrict__ encb)
{
    const int n = BB * LL * HH / 8;
    for (int i = blockIdx.x * 256 + threadIdx.x; i < n; i += gridDim.x * 256) {
        const float4 a = enc[2 * i], c = enc[2 * i + 1];
        uint4 o;
        o.x = bfr(a.x) | (bfr(a.y) << 16);
        o.y = bfr(a.z) | (bfr(a.w) << 16);
        o.z = bfr(c.x) | (bfr(c.y) << 16);
        o.w = bfr(c.z) | (bfr(c.w) << 16);
        encb[i] = o;
    }
}

// ---------------------------------------------------------------------------
// PROBE: attention streaming+compute core only (no epilogue, no LDS combine,
// no partial outputs). Launched 2x per step purely to measure the marginal
// cost of the attention core from dur_us: attn_core = (dur8 - dur7)/128.
// Writes to a dummy ws region to stay live. Identical wave layout / access
// pattern / register structure to attn_kernel's main loop.
// ---------------------------------------------------------------------------
__global__ __launch_bounds__(256) void attn_probe(
    const uint4* __restrict__ encb,
    const float* __restrict__ df,
    const float* __restrict__ v,
    const float* __restrict__ wc,
    float* __restrict__ dummy)
{
    const int g = blockIdx.x;
    const int b = g & (BB - 1);
    const int chunk = g >> 6;
    const int tid = threadIdx.x;
    const int wave = tid >> 6;
    const int lane = tid & 63;
    const int hc = lane & 15;
    const int lsub = lane >> 4;
    const int l0 = chunk * LCHUNK + wave * (LCHUNK / 4);

    float dfv[16], vv[16], wcv[16];
    #pragma unroll
    for (int k = 0; k < 2; ++k) {
        load8(df + b * HH + hc * 8 + 128 * k, dfv + 8 * k);
        load8(v + hc * 8 + 128 * k, vv + 8 * k);
        load8(wc + hc * 8 + 128 * k, wcv + 8 * k);
    }

    const uint4* ep0 = encb + (size_t)(b * LL + l0 + lsub) * 32 + hc;

    float s = 0.f;
    float cacc[16];
    #pragma unroll
    for (int j = 0; j < 16; ++j) cacc[j] = 0.f;

    uint4 eA0 = ep0[0], eA1 = ep0[16];

    #pragma unroll
    for (int mi = 0; mi < 4; ++mi) {
        uint4 eB0 = {0,0,0,0}, eB1 = {0,0,0,0};
        if (mi < 3) { eB0 = ep0[(mi + 1) * 128]; eB1 = ep0[(mi + 1) * 128 + 16]; }

        float fe[16];
        bf8x(eA0, fe); bf8x(eA1, fe + 8);
        float p = 0.f;
        #pragma unroll
        for (int j = 0; j < 16; ++j)
            p += vv[j] * ftanh(fe[j] + dfv[j] + 0.125f * wcv[j]);
        p += __shfl_xor(p, 1);
        p += __shfl_xor(p, 2);
        p += __shfl_xor(p, 4);
        p += __shfl_xor(p, 8);

        const float w = fexp(p);
        s += w;
        #pragma unroll
        for (int j = 0; j < 16; ++j) cacc[j] += w * fe[j];
        eA0 = eB0; eA1 = eB1;
    }

    float acc = s;
    #pragma unroll
    for (int j = 0; j < 16; ++j) acc += cacc[j];
    if (tid == 0) dummy[g] = acc;   // keep everything live
}

// ---------------------------------------------------------------------------
// K1: attention pass for step t (bf16 enc), fused with step-(t-1) epilogue.
// NO online max: |e| <= sum|v_h| ~ 20, exp(e) <= 5e8, fp32-safe.
// Grid: NCHUNK*BB = 2048 blocks, 256 threads.
// ---------------------------------------------------------------------------
__global__ __launch_bounds__(256) void attn_kernel(
    const uint4* __restrict__ encb,  // (B*L, 32) uint4 (=256 bf16 per row)
    const float* __restrict__ mask,
    float* __restrict__ cov,
    const float* __restrict__ df,
    const float* __restrict__ v,
    const float* __restrict__ wc,
    float* __restrict__ e_ws,        // (2,B,L)
    float* __restrict__ attns,
    const float* __restrict__ is_ws, // (B) prev-step 1/S
    float* __restrict__ sp, float* __restrict__ ctxp,
    int t)
{
    const int prev_t = t - 1;
    const int g = blockIdx.x;
    const int b = g & (BB - 1);
    const int chunk = g >> 6;
    const int tid = threadIdx.x;
    const int wave = tid >> 6;
    const int lane = tid & 63;
    const int hc = lane & 15;
    const int lsub = lane >> 4;
    const int l0 = chunk * LCHUNK + wave * (LCHUNK / 4);

    const float* e_prev = e_ws + (size_t)(prev_t & 1) * BB * LL;
    float* e_cur = e_ws + (size_t)(t & 1) * BB * LL;
    const float iSprev = (prev_t >= 0) ? is_ws[b] : 0.f;

    float mskv[4], covv[4], epv[4];
    #pragma unroll
    for (int mi = 0; mi < 4; ++mi) {
        const int idx = b * LL + l0 + mi * 4 + lsub;
        mskv[mi] = mask[idx];
        covv[mi] = (prev_t >= 0) ? cov[idx] : 0.f;
        epv[mi]  = (prev_t >= 0) ? e_prev[idx] : 0.f;
    }

    float dfv[16], vv[16], wcv[16];
    #pragma unroll
    for (int k = 0; k < 2; ++k) {
        load8(df + b * HH + hc * 8 + 128 * k, dfv + 8 * k);
        load8(v + hc * 8 + 128 * k, vv + 8 * k);
        load8(wc + hc * 8 + 128 * k, wcv + 8 * k);
    }

    float cvv[4];
    #pragma unroll
    for (int mi = 0; mi < 4; ++mi) {
        const int l = l0 + mi * 4 + lsub;
        const int idx = b * LL + l;
        if (prev_t >= 0) {
            const float a = fexp(epv[mi]) * mskv[mi] * iSprev;
            cvv[mi] = covv[mi] + a;
            if (hc == 0) {
                cov[idx] = cvv[mi];
                attns[((size_t)prev_t * BB + b) * LL + l] = a;
            }
        } else {
            cvv[mi] = 0.f;
            if (hc == 0) cov[idx] = 0.f;
        }
    }

    const uint4* ep0 = encb + (size_t)(b * LL + l0 + lsub) * 32 + hc;

    float s = 0.f;
    float cacc[16];
    #pragma unroll
    for (int j = 0; j < 16; ++j) cacc[j] = 0.f;

    uint4 eA0 = ep0[0], eA1 = ep0[16];

    #pragma unroll
    for (int mi = 0; mi < 4; ++mi) {
        uint4 eB0 = {0,0,0,0}, eB1 = {0,0,0,0};
        if (mi < 3) { eB0 = ep0[(mi + 1) * 128]; eB1 = ep0[(mi + 1) * 128 + 16]; }

        float fe[16];
        bf8x(eA0, fe); bf8x(eA1, fe + 8);
        float p = 0.f;
        #pragma unroll
        for (int j = 0; j < 16; ++j)
            p += vv[j] * ftanh(fe[j] + dfv[j] + cvv[mi] * wcv[j]);
        p += __shfl_xor(p, 1);
        p += __shfl_xor(p, 2);
        p += __shfl_xor(p, 4);
        p += __shfl_xor(p, 8);
        const int l = l0 + mi * 4 + lsub;
        if (hc == 0) e_cur[b * LL + l] = p;

        const float w = fexp(p) * mskv[mi];   // no max shift (bounded e)
        s += w;
        #pragma unroll
        for (int j = 0; j < 16; ++j) cacc[j] += w * fe[j];
        eA0 = eB0; eA1 = eB1;
    }

    // cross-subgroup butterfly: plain sums
    #pragma unroll
    for (int off = 16; off <= 32; off <<= 1) {
        s += __shfl_xor(s, off);
        #pragma unroll
        for (int j = 0; j < 16; ++j) cacc[j] += __shfl_xor(cacc[j], off);
    }

    __shared__ float lsum[4];
    __shared__ float lctx[4][HH];
    if (lsub == 0) {
        #pragma unroll
        for (int k = 0; k < 2; ++k)
            #pragma unroll
            for (int j = 0; j < 8; ++j)
                lctx[wave][hc * 8 + 128 * k + j] = cacc[k * 8 + j];
    }
    if (lane == 0) lsum[wave] = s;
    __syncthreads();

    const int pidx = chunk * BB + b;
    ctxp[(size_t)pidx * HH + tid] =
        lctx[0][tid] + lctx[1][tid] + lctx[2][tid] + lctx[3][tid];
    if (tid == 0)
        sp[pidx] = lsum[0] + lsum[1] + lsum[2] + lsum[3];
}

// ---------------------------------------------------------------------------
// K2: combine step-(t-1) partials -> ctx_{t-1}, then x_t. Grid BB, 256 thr.
// ---------------------------------------------------------------------------
__global__ __launch_bounds__(256) void ctx_x_kernel(
    const float* __restrict__ dec_in,
    const float* __restrict__ sp, const float* __restrict__ ctxp,
    const float* __restrict__ Wx, const float* __restrict__ bx,
    float* __restrict__ ctx_hist, float* __restrict__ x_hist,
    float* __restrict__ is_ws, int t)
{
    const int b = blockIdx.x;
    const int tid = threadIdx.x;
    __shared__ float sctx[HH], siv[EE], xred[EE];

    if (t > 0) {
        float S = 0.f, cs = 0.f;
        #pragma unroll
        for (int k = 0; k < NCHUNK; ++k) {
            S += sp[k * BB + b];
            cs += ctxp[(size_t)(k * BB + b) * HH + tid];
        }
        const float invS = 1.f / S;
        const float cx = cs * invS;
        sctx[tid] = cx;
        ctx_hist[((size_t)(t - 1) * BB + b) * HH + tid] = cx;
        if (tid == 0) is_ws[b] = invS;
    } else {
        sctx[tid] = 0.f;
    }
    if (t < T_STEPS && tid < EE)
        siv[tid] = dec_in[((size_t)t * BB + b) * EE + tid];
    __syncthreads();

    if (t < T_STEPS) {
        const int j = tid & 127, q = tid >> 7;
        float a = 0.f;
        #pragma unroll 4
        for (int r = q * 192; r < q * 192 + 192; ++r) {
            const float f = (r < EE) ? siv[r] : sctx[r - EE];
            a += f * Wx[(size_t)r * EE + j];
        }
        if (q) xred[j] = a;
        __syncthreads();
        if (!q)
            x_hist[((size_t)t * BB + b) * EE + j] = fmaxf(a + xred[j] + bx[j], 0.f);
    }
}

// ---------------------------------------------------------------------------
// K3: LSTM z-GEMM + (c,h) update. Grid 512 blocks = (u, half), 128 threads.
// ---------------------------------------------------------------------------
__global__ __launch_bounds__(128) void lstm_kernel(
    const float* __restrict__ x_hist,
    const float* __restrict__ init_c, const float* __restrict__ init_h,
    const float* __restrict__ Wl, const float* __restrict__ bl,
    float* __restrict__ c_hist, float* __restrict__ h_hist, int t)
{
    const int u = blockIdx.x >> 1;
    const int half = blockIdx.x & 1;
    const int tid = threadIdx.x;
    __shared__ float f[32 * 385];
    __shared__ float wl[4 * 385];
    __shared__ float zs[4 * 32];

    const float* hsrc = (t == 0) ? init_h : (h_hist + (size_t)(t - 1) * BB * HH);
    const float* csrc = (t == 0) ? init_c : (c_hist + (size_t)(t - 1) * BB * HH);

    for (int i = tid; i < 32 * 128; i += 128) {
        const int mm = i >> 7, k = i & 127;
        f[mm * 385 + k] = x_hist[((size_t)t * BB + half * 32 + mm) * EE + k];
    }
    for (int i = tid; i < 32 * 256; i += 128) {
        const int mm = i >> 8, k = i & 255;
        f[mm * 385 + 128 + k] = hsrc[(half * 32 + mm) * HH + k];
    }
    for (int i = tid; i < 4 * 384; i += 128) {
        const int gg = i / 384, k = i - gg * 384;
        wl[gg * 385 + k] = Wl[(size_t)k * 1024 + gg * 256 + u];
    }
    __syncthreads();

    const int mm = tid & 31, gg = tid >> 5;
    float acc = bl[gg * 256 + u];
    const float* fr = f + mm * 385;
    const float* wr = wl + gg * 385;
    #pragma unroll 8
    for (int k = 0; k < 384; ++k) acc += fr[k] * wr[k];
    zs[gg * 32 + mm] = acc;
    __syncthreads();

    if (tid < 32) {
        const int mg = half * 32 + tid;
        const float zi = zs[tid], zf = zs[32 + tid], zg = zs[64 + tid], zo = zs[96 + tid];
        const float cp = csrc[mg * HH + u];
        const float cn = fsig(zf) * cp + fsig(zi) * ftanh(zg);
        const float hn = fsig(zo) * ftanh(cn);
        c_hist[((size_t)t * BB + mg) * HH + u] = cn;
        h_hist[((size_t)t * BB + mg) * HH + u] = hn;
    }
}

// ---------------------------------------------------------------------------
// K4: dec_feat_t = tanh([c_t, h_t] @ W_s + b_s). Grid BB, 512 threads.
// ---------------------------------------------------------------------------
__global__ __launch_bounds__(512) void df_kernel(
    const float* __restrict__ c_hist, const float* __restrict__ h_hist,
    const float* __restrict__ Ws, const float* __restrict__ bs,
    float* __restrict__ df_ws, int t)
{
    const int b = blockIdx.x;
    const int tid = threadIdx.x;
    __shared__ float sf[512];
    __shared__ float rbuf[256];
    sf[tid] = (tid < 256) ? c_hist[((size_t)t * BB + b) * HH + tid]
                          : h_hist[((size_t)t * BB + b) * HH + tid - 256];
    __syncthreads();
    const int j = tid & 255, half = tid >> 8;
    float a = 0.f;
    const float* wcol = Ws + (size_t)(half * 256) * HH + j;
    const float* src = sf + half * 256;
    #pragma unroll 4
    for (int r = 0; r < 256; ++r) a += src[r] * wcol[(size_t)r * HH];
    if (half) rbuf[j] = a;
    __syncthreads();
    if (!half) df_ws[b * HH + j] = ftanh(a + rbuf[j] + bs[j]);
}

// ---------------------------------------------------------------------------
// K5: epilogue: attns[T-1], final cov, c/h outputs. Grid BB, 256 threads.
// ---------------------------------------------------------------------------
__global__ __launch_bounds__(256) void epi_kernel(
    const float* __restrict__ e_ws, const float* __restrict__ mask,
    const float* __restrict__ is_ws,
    const float* __restrict__ c_hist, const float* __restrict__ h_hist,
    float* __restrict__ attns, float* __restrict__ cov,
    float* __restrict__ c_out, float* __restrict__ h_out)
{
    const int b = blockIdx.x;
    const int j = threadIdx.x;
    const float iS = is_ws[b];
    const float* e_last = e_ws + (size_t)((T_STEPS - 1) & 1) * BB * LL;
    for (int i = 0; i < LL / 256; ++i) {
        const int l = i * 256 + j;
        const int idx = b * LL + l;
        const float a = fexp(e_last[idx]) * mask[idx] * iS;
        attns[((size_t)(T_STEPS - 1) * BB + b) * LL + l] = a;
        cov[idx] += a;
    }
    c_out[b * HH + j] = c_hist[((size_t)(T_STEPS - 1) * BB + b) * HH + j];
    h_out[b * HH + j] = h_hist[((size_t)(T_STEPS - 1) * BB + b) * HH + j];
}

// ---------------------------------------------------------------------------
// K6: batched outs + pgens. Grid 256 blocks = (t, b-quarter), 512 threads.
// ---------------------------------------------------------------------------
__global__ __launch_bounds__(512) void out_kernel(
    const float* __restrict__ h_hist, const float* __restrict__ ctx_hist,
    const float* __restrict__ c_hist, const float* __restrict__ x_hist,
    const float* __restrict__ Wo, const float* __restrict__ bo,
    const float* __restrict__ Wp, const float* __restrict__ bp,
    float* __restrict__ outs, float* __restrict__ pgens)
{
    const int t = blockIdx.x >> 2;
    const int bq = blockIdx.x & 3;
    const int tid = threadIdx.x;
    __shared__ float hs[16 * 256], cts[16 * 256], cs2[16 * 256], xs[16 * 128];
    __shared__ float zbuf[16 * 256];

    for (int i = tid; i < 16 * 256; i += 512) {
        const int bl = i >> 8, j = i & 255;
        const size_t row = ((size_t)t * BB + bq * 16 + bl) * HH;
        hs[i] = h_hist[row + j];
        cts[i] = ctx_hist[row + j];
        cs2[i] = c_hist[row + j];
    }
    for (int i = tid; i < 16 * 128; i += 512) {
        const int bl = i >> 7, j = i & 127;
        xs[i] = x_hist[((size_t)t * BB + bq * 16 + bl) * EE + j];
    }
    __syncthreads();

    {
        const int j = tid & 255, rh = tid >> 8;
        float acc[16];
        #pragma unroll
        for (int bl = 0; bl < 16; ++bl) acc[bl] = 0.f;
        const int r0 = rh * 128;
        #pragma unroll 4
        for (int r = r0; r < r0 + 128; ++r) {
            const float w0 = Wo[(size_t)r * HH + j];
            const float w1 = Wo[(size_t)(256 + r) * HH + j];
            #pragma unroll
            for (int bl = 0; bl < 16; ++bl)
                acc[bl] += hs[bl * 256 + r] * w0 + cts[bl * 256 + r] * w1;
        }
        if (rh) {
            #pragma unroll
            for (int bl = 0; bl < 16; ++bl) zbuf[bl * 256 + j] = acc[bl];
        }
        __syncthreads();
        if (!rh) {
            #pragma unroll
            for (int bl = 0; bl < 16; ++bl)
                outs[((size_t)t * BB + bq * 16 + bl) * HH + j] =
                    acc[bl] + zbuf[bl * 256 + j] + bo[j];
        }
    }

    {
        const int bl = tid >> 5, r32 = tid & 31;
        float p = 0.f;
        for (int i = r32; i < 256; i += 32)
            p += cts[bl * 256 + i] * Wp[i] + cs2[bl * 256 + i] * Wp[256 + i]
               + hs[bl * 256 + i] * Wp[512 + i];
        for (int i = r32; i < 128; i += 32)
            p += xs[bl * 128 + i] * Wp[768 + i];
        p += __shfl_xor(p, 1);
        p += __shfl_xor(p, 2);
        p += __shfl_xor(p, 4);
        p += __shfl_xor(p, 8);
        p += __shfl_xor(p, 16);
        if (r32 == 0)
            pgens[(size_t)t * BB + bq * 16 + bl] = fsig(p + bp[0]);
    }
}

extern "C" void kernel_launch(void* const* d_in, const int* in_sizes, int n_in,
                              void* d_out, int out_size, void* d_ws, size_t ws_size,
                              hipStream_t stream) {
    const float* dec_in = (const float*)d_in[0];
    const float* init_c = (const float*)d_in[1];
    const float* init_h = (const float*)d_in[2];
    const float* enc    = (const float*)d_in[3];
    const float* mask   = (const float*)d_in[4];
    const float* Wx = (const float*)d_in[5];
    const float* bx = (const float*)d_in[6];
    const float* Wl = (const float*)d_in[7];
    const float* bl = (const float*)d_in[8];
    const float* Ws = (const float*)d_in[9];
    const float* bs = (const float*)d_in[10];
    const float* v  = (const float*)d_in[11];
    const float* wc = (const float*)d_in[12];
    const float* Wp = (const float*)d_in[13];
    const float* bp = (const float*)d_in[14];
    const float* Wo = (const float*)d_in[15];
    const float* bo = (const float*)d_in[16];

    float* out   = (float*)d_out;
    float* outs  = out;                                   // T*B*H
    float* c_out = outs + (size_t)T_STEPS * BB * HH;      // B*H
    float* h_out = c_out + BB * HH;                       // B*H
    float* attns = h_out + BB * HH;                       // T*B*L
    float* pgens = attns + (size_t)T_STEPS * BB * LL;     // T*B
    float* cov   = pgens + T_STEPS * BB;                  // B*L

    float* ws     = (float*)d_ws;
    uint4* encb   = (uint4*)ws;                           // B*L*H bf16
    float* e_ws   = ws + (size_t)BB * LL * HH / 2;        // 2*B*L
    float* sp     = e_ws + 2 * BB * LL;                   // 32*B
    float* ctxp   = sp + NCHUNK * BB;                     // 32*B*H
    float* x_hist = ctxp + (size_t)NCHUNK * BB * HH;      // T*B*E
    float* df_ws  = x_hist + (size_t)T_STEPS * BB * EE;   // B*H
    float* is_ws  = df_ws + BB * HH;                      // B
    float* ctx_hist = is_ws + BB;                         // T*B*H
    float* c_hist = ctx_hist + (size_t)T_STEPS * BB * HH; // T*B*H
    float* h_hist = c_hist + (size_t)T_STEPS * BB * HH;   // T*B*H
    float* dummy  = h_hist + (size_t)T_STEPS * BB * HH;   // NCHUNK*B probe sink

    conv_kernel<<<4096, 256, 0, stream>>>((const float4*)enc, encb);

    for (int t = 0; t < T_STEPS; ++t) {
        ctx_x_kernel<<<BB, 256, 0, stream>>>(dec_in, sp, ctxp, Wx, bx,
            ctx_hist, x_hist, is_ws, t);
        lstm_kernel<<<512, 128, 0, stream>>>(x_hist, init_c, init_h, Wl, bl,
            c_hist, h_hist, t);
        df_kernel<<<BB, 512, 0, stream>>>(c_hist, h_hist, Ws, bs, df_ws, t);
        attn_kernel<<<NCHUNK * BB, 256, 0, stream>>>(encb, mask, cov, df_ws,
            v, wc, e_ws, attns, is_ws, sp, ctxp, t);
        // diagnostic probes: marginal cost of the attention core, x2
        attn_probe<<<NCHUNK * BB, 256, 0, stream>>>(encb, df_ws, v, wc, dummy);
        attn_probe<<<NCHUNK * BB, 256, 0, stream>>>(encb, df_ws, v, wc, dummy);
    }
    ctx_x_kernel<<<BB, 256, 0, stream>>>(dec_in, sp, ctxp, Wx, bx,
        ctx_hist, x_hist, is_ws, T_STEPS);
    epi_kernel<<<BB, 256, 0, stream>>>(e_ws, mask, is_ws,
        c_hist, h_hist, attns, cov, c_out, h_out);
    out_kernel<<<256, 512, 0, stream>>>(h_hist, ctx_hist, c_hist, x_hist,
        Wo, bo, Wp, bp, outs, pgens);
}

// Round 10
// 4616.632 us; speedup vs baseline: 1.4803x; 1.4803x over previous
//
#include <hip/hip_runtime.h>
#include <hip/hip_cooperative_groups.h>
#include <math.h>

namespace cg = cooperative_groups;

#define T_STEPS 64
#define BB 64
#define LL 2048
#define EE 128
#define HH 256
#define NCHUNK 32
#define LCHUNK (LL / NCHUNK) /* 64 */
#define NBLK 512
#define NTHR 256

__device__ __forceinline__ float fexp(float x) {
    return __builtin_amdgcn_exp2f(x * 1.44269504088896340736f);
}
__device__ __forceinline__ float fsig(float x) {
    return __builtin_amdgcn_rcpf(1.f + __builtin_amdgcn_exp2f(-1.44269504088896340736f * x));
}
__device__ __forceinline__ float ftanh(float x) {
    float xc = fminf(fmaxf(x, -20.f), 20.f);
    float p = __builtin_amdgcn_exp2f(2.885390081777926814f * xc); // e^{2x}
    return (p - 1.f) * __builtin_amdgcn_rcpf(p + 1.f);
}
__device__ __forceinline__ unsigned int bfr(float x) {
    unsigned int u = __float_as_uint(x);
    return (u + 0x7FFFu + ((u >> 16) & 1u)) >> 16;
}
__device__ __forceinline__ void bf8x(const uint4 q, float* f) {
    f[0] = __uint_as_float(q.x << 16); f[1] = __uint_as_float(q.x & 0xFFFF0000u);
    f[2] = __uint_as_float(q.y << 16); f[3] = __uint_as_float(q.y & 0xFFFF0000u);
    f[4] = __uint_as_float(q.z << 16); f[5] = __uint_as_float(q.z & 0xFFFF0000u);
    f[6] = __uint_as_float(q.w << 16); f[7] = __uint_as_float(q.w & 0xFFFF0000u);
}
__device__ __forceinline__ void load8(const float* p, float* d) {
    float4 a = *(const float4*)p, b = *(const float4*)(p + 4);
    d[0]=a.x; d[1]=a.y; d[2]=a.z; d[3]=a.w; d[4]=b.x; d[5]=b.y; d[6]=b.z; d[7]=b.w;
}

struct KParams {
    const float *dec_in, *init_c, *init_h, *enc, *mask;
    const float *Wx, *bx, *Wl, *bl, *Ws, *bs, *v, *wc, *Wp, *bp, *Wo, *bo;
    float *outs, *c_out, *h_out, *attns, *pgens, *cov;
    uint4 *encb;
    float *e_ws, *ctx_acc, *S_acc, *x_hist, *df_ws, *is_ws, *ctx_hist, *c_hist, *h_hist;
};

// ===========================================================================
// Cooperative mega-kernel. 512 blocks x 256 threads, LDS 29.3 KB/block
// (2 blocks/CU even under a 64KB-LDS occupancy model -> coop launch valid).
// Per step: attn (all blocks, atomic partials) S P2(ctx+x, 0-63) S
// P3(z 0-127 | outs 192-255 | pgens 256-319) S P4(df 128-191) S.
// ===========================================================================
__global__ __launch_bounds__(NTHR, 2) void mega_kernel(KParams p)
{
    cg::grid_group grid = cg::this_grid();
    const int G = blockIdx.x;
    const int tid = threadIdx.x;

    __shared__ float pw[3080];   // z-blocks: 8x385 Wl cols; df/out: 4x513
    __shared__ float scr[4240];  // attn 1028 | z stage 8x385+red | df/out 8x513+red

    // ---- persistent weight slices ----
    if (G < 128) {
        const int u0 = G * 2;
        for (int i = tid; i < 8 * 384; i += NTHR) {
            const int c = i / 384, k = i - c * 384;
            const int col = (c >> 1) * 256 + u0 + (c & 1);
            pw[c * 385 + k] = p.Wl[(size_t)k * 1024 + col];
        }
    } else if (G < 192) {
        const int col0 = (G - 128) * 4;
        for (int i = tid; i < 4 * 512; i += NTHR) {
            const int c = i >> 9, k = i & 511;
            pw[c * 513 + k] = p.Ws[(size_t)k * HH + col0 + c];
        }
    } else if (G < 256) {
        const int col0 = (G - 192) * 4;
        for (int i = tid; i < 4 * 512; i += NTHR) {
            const int c = i >> 9, k = i & 511;
            pw[c * 513 + k] = p.Wo[(size_t)k * HH + col0 + c];
        }
    }

    // ---- conv: fp32 enc -> bf16 ----
    {
        const int n = BB * LL * HH / 8;
        const float4* e4 = (const float4*)p.enc;
        for (int i = G * NTHR + tid; i < n; i += NBLK * NTHR) {
            const float4 a = e4[2 * i], c = e4[2 * i + 1];
            uint4 o;
            o.x = bfr(a.x) | (bfr(a.y) << 16);
            o.y = bfr(a.z) | (bfr(a.w) << 16);
            o.z = bfr(c.x) | (bfr(c.y) << 16);
            o.w = bfr(c.z) | (bfr(c.w) << 16);
            p.encb[i] = o;
        }
    }

    // attention for step t; fused step-(t-1) epilogue (attns/cov rmw).
    auto phaseAttn = [&](int t) {
        const int b = G & 63;
        const int chunk = G >> 6;          // 0..7, 256 l-rows each
        const int wave = tid >> 6;
        const int lane = tid & 63;
        const int hc = lane & 15;
        const int lsub = lane >> 4;
        const int l0 = chunk * 256 + wave * 64;
        const float* e_prev = p.e_ws + (size_t)((t - 1) & 1) * BB * LL;
        float* e_cur = p.e_ws + (size_t)(t & 1) * BB * LL;
        const float iSprev = (t > 0) ? p.is_ws[b] : 0.f;

        float dfv[16], vv[16], wcv[16];
        #pragma unroll
        for (int k = 0; k < 2; ++k) {
            load8(p.df_ws + b * HH + hc * 8 + 128 * k, dfv + 8 * k);
            load8(p.v + hc * 8 + 128 * k, vv + 8 * k);
            load8(p.wc + hc * 8 + 128 * k, wcv + 8 * k);
        }

        const uint4* ep0 = p.encb + (size_t)(b * LL + l0 + lsub) * 32 + hc;

        auto scal = [&](int mi, float& cv, float& msk) {
            const int l = l0 + mi * 4 + lsub;
            const int idx = b * LL + l;
            msk = p.mask[idx];
            if (t > 0) {
                const float a = fexp(e_prev[idx]) * msk * iSprev;
                cv = p.cov[idx] + a;
                if (hc == 0) {
                    p.cov[idx] = cv;
                    p.attns[((size_t)(t - 1) * BB + b) * LL + l] = a;
                }
            } else {
                cv = 0.f;
                if (hc == 0) p.cov[idx] = 0.f;
            }
        };

        float s = 0.f;
        float cacc[16];
        #pragma unroll
        for (int j = 0; j < 16; ++j) cacc[j] = 0.f;

        float cvA, mskA;
        scal(0, cvA, mskA);
        uint4 eA0 = ep0[0], eA1 = ep0[16];

        for (int mi = 0; mi < 16; ++mi) {
            float cvB = 0.f, mskB = 0.f;
            uint4 eB0 = {0,0,0,0}, eB1 = {0,0,0,0};
            if (mi < 15) {
                scal(mi + 1, cvB, mskB);
                const uint4* epn = ep0 + (mi + 1) * 128;
                eB0 = epn[0]; eB1 = epn[16];
            }
            float fe[16];
            bf8x(eA0, fe); bf8x(eA1, fe + 8);
            float pp = 0.f;
            #pragma unroll
            for (int j = 0; j < 16; ++j)
                pp += vv[j] * ftanh(fe[j] + dfv[j] + cvA * wcv[j]);
            pp += __shfl_xor(pp, 1);
            pp += __shfl_xor(pp, 2);
            pp += __shfl_xor(pp, 4);
            pp += __shfl_xor(pp, 8);
            const int l = l0 + mi * 4 + lsub;
            if (hc == 0) e_cur[b * LL + l] = pp;

            const float w = fexp(pp) * mskA;   // bounded e -> no max shift
            s += w;
            #pragma unroll
            for (int j = 0; j < 16; ++j) cacc[j] += w * fe[j];
            cvA = cvB; mskA = mskB; eA0 = eB0; eA1 = eB1;
        }

        #pragma unroll
        for (int off = 16; off <= 32; off <<= 1) {
            s += __shfl_xor(s, off);
            #pragma unroll
            for (int j = 0; j < 16; ++j) cacc[j] += __shfl_xor(cacc[j], off);
        }

        if (lsub == 0) {
            #pragma unroll
            for (int k = 0; k < 2; ++k)
                #pragma unroll
                for (int j = 0; j < 8; ++j)
                    scr[wave * 256 + hc * 8 + 128 * k + j] = cacc[k * 8 + j];
        }
        if (lane == 0) scr[1024 + wave] = s;
        __syncthreads();
        const float val = scr[tid] + scr[256 + tid] + scr[512 + tid] + scr[768 + tid];
        atomicAdd(&p.ctx_acc[b * HH + tid], val);
        if (tid == 0)
            atomicAdd(&p.S_acc[b], scr[1024] + scr[1025] + scr[1026] + scr[1027]);
        __syncthreads();
    };

    // P2 (blocks 0..63): ctx(t), zero accs, x(t+1).
    auto phaseP2 = [&](int t) {
        const int b = G;
        const float cs = p.ctx_acc[b * HH + tid];
        const float S = p.S_acc[b];
        const float invS = 1.f / S;
        const float cx = cs * invS;
        p.ctx_hist[((size_t)t * BB + b) * HH + tid] = cx;
        p.ctx_acc[b * HH + tid] = 0.f;
        if (tid == 0) { p.S_acc[b] = 0.f; p.is_ws[b] = invS; }
        if (t < T_STEPS - 1) {
            scr[128 + tid] = cx;
            if (tid < EE) scr[tid] = p.dec_in[((size_t)(t + 1) * BB + b) * EE + tid];
            __syncthreads();
            const int j = tid & 127, q = tid >> 7;
            float a = 0.f;
            #pragma unroll 4
            for (int r = q * 192; r < q * 192 + 192; ++r)
                a += scr[r] * p.Wx[(size_t)r * EE + j];
            if (q) scr[1024 + j] = a;
            __syncthreads();
            if (!q) p.x_hist[((size_t)(t + 1) * BB + b) * EE + j] =
                fmaxf(a + scr[1024 + j] + p.bx[j], 0.f);
        }
    };

    // P2pre (blocks 0..63): zero accs, x(0) (ctx = 0).
    auto phaseP2pre = [&]() {
        const int b = G;
        p.ctx_acc[b * HH + tid] = 0.f;
        if (tid == 0) p.S_acc[b] = 0.f;
        scr[128 + tid] = 0.f;
        if (tid < EE) scr[tid] = p.dec_in[(size_t)b * EE + tid];
        __syncthreads();
        const int j = tid & 127, q = tid >> 7;
        float a = 0.f;
        #pragma unroll 4
        for (int r = q * 192; r < q * 192 + 192; ++r)
            a += scr[r] * p.Wx[(size_t)r * EE + j];
        if (q) scr[1024 + j] = a;
        __syncthreads();
        if (!q) p.x_hist[(size_t)b * EE + j] =
            fmaxf(a + scr[1024 + j] + p.bx[j], 0.f);
    };

    // P3-z (blocks 0..127): z + c/h for 2 units x 64 batches, 8 b/pass.
    auto phaseZ = [&](int tau) {
        const int u0 = G * 2;
        const float* hsrc = (tau == 0) ? p.init_h : p.h_hist + (size_t)(tau - 1) * BB * HH;
        const float* csrc = (tau == 0) ? p.init_c : p.c_hist + (size_t)(tau - 1) * BB * HH;
        const float* xsrc = p.x_hist + (size_t)tau * BB * EE;
        for (int bp8 = 0; bp8 < 8; ++bp8) {
            for (int i = tid; i < 8 * EE; i += NTHR) {
                const int mm = i >> 7, k = i & 127;
                scr[mm * 385 + k] = xsrc[(size_t)(bp8 * 8 + mm) * EE + k];
            }
            for (int i = tid; i < 8 * HH; i += NTHR) {
                const int mm = i >> 8, k = i & 255;
                scr[mm * 385 + 128 + k] = hsrc[(size_t)(bp8 * 8 + mm) * HH + k];
            }
            __syncthreads();
            if (tid < 128) {
                const int b8 = tid & 7, c = (tid >> 3) & 7, kh = tid >> 6;
                const float* fr = scr + b8 * 385 + kh * 192;
                const float* wr = pw + c * 385 + kh * 192;
                float acc = 0.f;
                #pragma unroll 8
                for (int k = 0; k < 192; ++k) acc += fr[k] * wr[k];
                scr[3080 + kh * 64 + c * 8 + b8] = acc;
            }
            __syncthreads();
            if (tid < 64) {
                const int b8 = tid & 7, c = tid >> 3;
                const int zcol = (c >> 1) * 256 + u0 + (c & 1);
                scr[3208 + (bp8 * 8 + b8) * 8 + c] =
                    p.bl[zcol] + scr[3080 + c * 8 + b8] + scr[3144 + c * 8 + b8];
            }
            __syncthreads();
        }
        if (tid < 128) {
            const int b = tid >> 1, ui = tid & 1;
            const int u = u0 + ui;
            const float zi = scr[3208 + b * 8 + ui],     zf = scr[3208 + b * 8 + 2 + ui],
                        zg = scr[3208 + b * 8 + 4 + ui], zo = scr[3208 + b * 8 + 6 + ui];
            const float cp = csrc[(size_t)b * HH + u];
            const float cn = fsig(zf) * cp + fsig(zi) * ftanh(zg);
            const float hn = fsig(zo) * ftanh(cn);
            p.c_hist[((size_t)tau * BB + b) * HH + u] = cn;
            p.h_hist[((size_t)tau * BB + b) * HH + u] = hn;
        }
    };

    // generic [A,B] @ pw(4x513) GEMM, 8 rows/pass; df (tanh->df_ws) / out.
    auto gemm513 = [&](const float* A, const float* B, const float* bias,
                       int col0, float* dst, size_t dstStride, bool doTanh) {
        for (int bp8 = 0; bp8 < 8; ++bp8) {
            for (int i = tid; i < 8 * 512; i += NTHR) {
                const int mm = i >> 9, k = i & 511;
                scr[mm * 513 + k] = (k < 256) ? A[(size_t)(bp8 * 8 + mm) * HH + k]
                                              : B[(size_t)(bp8 * 8 + mm) * HH + k - 256];
            }
            __syncthreads();
            if (tid < 128) {
                const int b8 = tid & 7, c = (tid >> 3) & 3, kq = tid >> 5;
                const float* fr = scr + b8 * 513 + kq * 128;
                const float* wr = pw + c * 513 + kq * 128;
                float acc = 0.f;
                #pragma unroll 8
                for (int k = 0; k < 128; ++k) acc += fr[k] * wr[k];
                scr[4104 + kq * 32 + c * 8 + b8] = acc;
            }
            __syncthreads();
            if (tid < 32) {
                const int b8 = tid & 7, c = tid >> 3;
                const float z = scr[4104 + c * 8 + b8] + scr[4136 + c * 8 + b8]
                              + scr[4168 + c * 8 + b8] + scr[4200 + c * 8 + b8]
                              + bias[col0 + c];
                dst[(size_t)(bp8 * 8 + b8) * dstStride + col0 + c] = doTanh ? ftanh(z) : z;
            }
            __syncthreads();
        }
    };

    // P3-pgen (blocks 256..319).
    auto phasePGEN = [&](int t) {
        const int b = G - 256;
        const size_t rb = ((size_t)t * BB + b) * HH;
        float pp = p.ctx_hist[rb + tid] * p.Wp[tid]
                 + p.c_hist[rb + tid] * p.Wp[256 + tid]
                 + p.h_hist[rb + tid] * p.Wp[512 + tid];
        if (tid < EE) pp += p.x_hist[((size_t)t * BB + b) * EE + tid] * p.Wp[768 + tid];
        #pragma unroll
        for (int off = 32; off; off >>= 1) pp += __shfl_xor(pp, off);
        if ((tid & 63) == 0) scr[1024 + (tid >> 6)] = pp;
        __syncthreads();
        if (tid == 0)
            p.pgens[(size_t)t * BB + b] =
                fsig(scr[1024] + scr[1025] + scr[1026] + scr[1027] + p.bp[0]);
        __syncthreads();
    };

    auto phaseTail = [&]() {
        const int b = G & 63, sl = G >> 6;
        const float iS = p.is_ws[b];
        const float* e_last = p.e_ws + (size_t)((T_STEPS - 1) & 1) * BB * LL;
        const int l = sl * 256 + tid;
        const int idx = b * LL + l;
        const float a = fexp(e_last[idx]) * p.mask[idx] * iS;
        p.attns[((size_t)(T_STEPS - 1) * BB + b) * LL + l] = a;
        p.cov[idx] += a;
        if (G < BB) {
            p.c_out[(size_t)G * HH + tid] = p.c_hist[((size_t)(T_STEPS - 1) * BB + G) * HH + tid];
            p.h_out[(size_t)G * HH + tid] = p.h_hist[((size_t)(T_STEPS - 1) * BB + G) * HH + tid];
        }
    };

    // ---- schedule ----
    grid.sync();
    if (G < BB) phaseP2pre();
    grid.sync();
    if (G < 128) phaseZ(0);
    grid.sync();
    if (G >= 128 && G < 192)
        gemm513(p.c_hist, p.h_hist, p.bs, (G - 128) * 4, p.df_ws, HH, true);
    grid.sync();

    for (int t = 0; t < T_STEPS; ++t) {
        phaseAttn(t);
        grid.sync();
        if (G < BB) phaseP2(t);
        grid.sync();
        if (G < 128) { if (t < T_STEPS - 1) phaseZ(t + 1); }
        else if (G >= 192 && G < 256)
            gemm513(p.h_hist + (size_t)t * BB * HH, p.ctx_hist + (size_t)t * BB * HH,
                    p.bo, (G - 192) * 4, p.outs + (size_t)t * BB * HH, HH, false);
        else if (G >= 256 && G < 320) phasePGEN(t);
        grid.sync();
        if (t < T_STEPS - 1) {
            if (G >= 128 && G < 192)
                gemm513(p.c_hist + (size_t)(t + 1) * BB * HH,
                        p.h_hist + (size_t)(t + 1) * BB * HH,
                        p.bs, (G - 128) * 4, p.df_ws, HH, true);
        } else {
            phaseTail();
        }
        grid.sync();
    }
}

// ===========================================================================
// Fallback path (r7, proven passing at 4611 us).
// ===========================================================================
__global__ __launch_bounds__(256) void conv_kernel(
    const float4* __restrict__ enc, uint4* __restrict__ encb)
{
    const int n = BB * LL * HH / 8;
    for (int i = blockIdx.x * 256 + threadIdx.x; i < n; i += gridDim.x * 256) {
        const float4 a = enc[2 * i], c = enc[2 * i + 1];
        uint4 o;
        o.x = bfr(a.x) | (bfr(a.y) << 16);
        o.y = bfr(a.z) | (bfr(a.w) << 16);
        o.z = bfr(c.x) | (bfr(c.y) << 16);
        o.w = bfr(c.z) | (bfr(c.w) << 16);
        encb[i] = o;
    }
}

__global__ __launch_bounds__(256) void attn_kernel(
    const uint4* __restrict__ encb, const float* __restrict__ mask,
    float* __restrict__ cov, const float* __restrict__ df,
    const float* __restrict__ v, const float* __restrict__ wc,
    float* __restrict__ e_ws, float* __restrict__ attns,
    const float* __restrict__ is_ws,
    float* __restrict__ sp, float* __restrict__ ctxp, int t)
{
    const int prev_t = t - 1;
    const int g = blockIdx.x;
    const int b = g & (BB - 1);
    const int chunk = g >> 6;
    const int tid = threadIdx.x;
    const int wave = tid >> 6;
    const int lane = tid & 63;
    const int hc = lane & 15;
    const int lsub = lane >> 4;
    const int l0 = chunk * LCHUNK + wave * (LCHUNK / 4);

    const float* e_prev = e_ws + (size_t)(prev_t & 1) * BB * LL;
    float* e_cur = e_ws + (size_t)(t & 1) * BB * LL;
    const float iSprev = (prev_t >= 0) ? is_ws[b] : 0.f;

    float mskv[4], covv[4], epv[4];
    #pragma unroll
    for (int mi = 0; mi < 4; ++mi) {
        const int idx = b * LL + l0 + mi * 4 + lsub;
        mskv[mi] = mask[idx];
        covv[mi] = (prev_t >= 0) ? cov[idx] : 0.f;
        epv[mi]  = (prev_t >= 0) ? e_prev[idx] : 0.f;
    }

    float dfv[16], vv[16], wcv[16];
    #pragma unroll
    for (int k = 0; k < 2; ++k) {
        load8(df + b * HH + hc * 8 + 128 * k, dfv + 8 * k);
        load8(v + hc * 8 + 128 * k, vv + 8 * k);
        load8(wc + hc * 8 + 128 * k, wcv + 8 * k);
    }

    float cvv[4];
    #pragma unroll
    for (int mi = 0; mi < 4; ++mi) {
        const int l = l0 + mi * 4 + lsub;
        const int idx = b * LL + l;
        if (prev_t >= 0) {
            const float a = fexp(epv[mi]) * mskv[mi] * iSprev;
            cvv[mi] = covv[mi] + a;
            if (hc == 0) {
                cov[idx] = cvv[mi];
                attns[((size_t)prev_t * BB + b) * LL + l] = a;
            }
        } else {
            cvv[mi] = 0.f;
            if (hc == 0) cov[idx] = 0.f;
        }
    }

    const uint4* ep0 = encb + (size_t)(b * LL + l0 + lsub) * 32 + hc;

    float s = 0.f;
    float cacc[16];
    #pragma unroll
    for (int j = 0; j < 16; ++j) cacc[j] = 0.f;

    uint4 eA0 = ep0[0], eA1 = ep0[16];

    #pragma unroll
    for (int mi = 0; mi < 4; ++mi) {
        uint4 eB0 = {0,0,0,0}, eB1 = {0,0,0,0};
        if (mi < 3) { eB0 = ep0[(mi + 1) * 128]; eB1 = ep0[(mi + 1) * 128 + 16]; }

        float fe[16];
        bf8x(eA0, fe); bf8x(eA1, fe + 8);
        float pp = 0.f;
        #pragma unroll
        for (int j = 0; j < 16; ++j)
            pp += vv[j] * ftanh(fe[j] + dfv[j] + cvv[mi] * wcv[j]);
        pp += __shfl_xor(pp, 1);
        pp += __shfl_xor(pp, 2);
        pp += __shfl_xor(pp, 4);
        pp += __shfl_xor(pp, 8);
        const int l = l0 + mi * 4 + lsub;
        if (hc == 0) e_cur[b * LL + l] = pp;

        const float w = fexp(pp) * mskv[mi];
        s += w;
        #pragma unroll
        for (int j = 0; j < 16; ++j) cacc[j] += w * fe[j];
        eA0 = eB0; eA1 = eB1;
    }

    #pragma unroll
    for (int off = 16; off <= 32; off <<= 1) {
        s += __shfl_xor(s, off);
        #pragma unroll
        for (int j = 0; j < 16; ++j) cacc[j] += __shfl_xor(cacc[j], off);
    }

    __shared__ float lsum[4];
    __shared__ float lctx[4][HH];
    if (lsub == 0) {
        #pragma unroll
        for (int k = 0; k < 2; ++k)
            #pragma unroll
            for (int j = 0; j < 8; ++j)
                lctx[wave][hc * 8 + 128 * k + j] = cacc[k * 8 + j];
    }
    if (lane == 0) lsum[wave] = s;
    __syncthreads();

    const int pidx = chunk * BB + b;
    ctxp[(size_t)pidx * HH + tid] =
        lctx[0][tid] + lctx[1][tid] + lctx[2][tid] + lctx[3][tid];
    if (tid == 0)
        sp[pidx] = lsum[0] + lsum[1] + lsum[2] + lsum[3];
}

__global__ __launch_bounds__(256) void ctx_x_kernel(
    const float* __restrict__ dec_in,
    const float* __restrict__ sp, const float* __restrict__ ctxp,
    const float* __restrict__ Wx, const float* __restrict__ bx,
    float* __restrict__ ctx_hist, float* __restrict__ x_hist,
    float* __restrict__ is_ws, int t)
{
    const int b = blockIdx.x;
    const int tid = threadIdx.x;
    __shared__ float sctx[HH], siv[EE], xred[EE];

    if (t > 0) {
        float S = 0.f, cs = 0.f;
        #pragma unroll
        for (int k = 0; k < NCHUNK; ++k) {
            S += sp[k * BB + b];
            cs += ctxp[(size_t)(k * BB + b) * HH + tid];
        }
        const float invS = 1.f / S;
        const float cx = cs * invS;
        sctx[tid] = cx;
        ctx_hist[((size_t)(t - 1) * BB + b) * HH + tid] = cx;
        if (tid == 0) is_ws[b] = invS;
    } else {
        sctx[tid] = 0.f;
    }
    if (t < T_STEPS && tid < EE)
        siv[tid] = dec_in[((size_t)t * BB + b) * EE + tid];
    __syncthreads();

    if (t < T_STEPS) {
        const int j = tid & 127, q = tid >> 7;
        float a = 0.f;
        #pragma unroll 4
        for (int r = q * 192; r < q * 192 + 192; ++r) {
            const float f = (r < EE) ? siv[r] : sctx[r - EE];
            a += f * Wx[(size_t)r * EE + j];
        }
        if (q) xred[j] = a;
        __syncthreads();
        if (!q)
            x_hist[((size_t)t * BB + b) * EE + j] = fmaxf(a + xred[j] + bx[j], 0.f);
    }
}

__global__ __launch_bounds__(128) void lstm_kernel(
    const float* __restrict__ x_hist,
    const float* __restrict__ init_c, const float* __restrict__ init_h,
    const float* __restrict__ Wl, const float* __restrict__ bl,
    float* __restrict__ c_hist, float* __restrict__ h_hist, int t)
{
    const int u = blockIdx.x >> 1;
    const int half = blockIdx.x & 1;
    const int tid = threadIdx.x;
    __shared__ float f[32 * 385];
    __shared__ float wl[4 * 385];
    __shared__ float zs[4 * 32];

    const float* hsrc = (t == 0) ? init_h : (h_hist + (size_t)(t - 1) * BB * HH);
    const float* csrc = (t == 0) ? init_c : (c_hist + (size_t)(t - 1) * BB * HH);

    for (int i = tid; i < 32 * 128; i += 128) {
        const int mm = i >> 7, k = i & 127;
        f[mm * 385 + k] = x_hist[((size_t)t * BB + half * 32 + mm) * EE + k];
    }
    for (int i = tid; i < 32 * 256; i += 128) {
        const int mm = i >> 8, k = i & 255;
        f[mm * 385 + 128 + k] = hsrc[(half * 32 + mm) * HH + k];
    }
    for (int i = tid; i < 4 * 384; i += 128) {
        const int gg = i / 384, k = i - gg * 384;
        wl[gg * 385 + k] = Wl[(size_t)k * 1024 + gg * 256 + u];
    }
    __syncthreads();

    const int mm = tid & 31, gg = tid >> 5;
    float acc = bl[gg * 256 + u];
    const float* fr = f + mm * 385;
    const float* wr = wl + gg * 385;
    #pragma unroll 8
    for (int k = 0; k < 384; ++k) acc += fr[k] * wr[k];
    zs[gg * 32 + mm] = acc;
    __syncthreads();

    if (tid < 32) {
        const int mg = half * 32 + tid;
        const float zi = zs[tid], zf = zs[32 + tid], zg = zs[64 + tid], zo = zs[96 + tid];
        const float cp = csrc[mg * HH + u];
        const float cn = fsig(zf) * cp + fsig(zi) * ftanh(zg);
        const float hn = fsig(zo) * ftanh(cn);
        c_hist[((size_t)t * BB + mg) * HH + u] = cn;
        h_hist[((size_t)t * BB + mg) * HH + u] = hn;
    }
}

__global__ __launch_bounds__(512) void df_kernel(
    const float* __restrict__ c_hist, const float* __restrict__ h_hist,
    const float* __restrict__ Ws, const float* __restrict__ bs,
    float* __restrict__ df_ws, int t)
{
    const int b = blockIdx.x;
    const int tid = threadIdx.x;
    __shared__ float sf[512];
    __shared__ float rbuf[256];
    sf[tid] = (tid < 256) ? c_hist[((size_t)t * BB + b) * HH + tid]
                          : h_hist[((size_t)t * BB + b) * HH + tid - 256];
    __syncthreads();
    const int j = tid & 255, half = tid >> 8;
    float a = 0.f;
    const float* wcol = Ws + (size_t)(half * 256) * HH + j;
    const float* src = sf + half * 256;
    #pragma unroll 4
    for (int r = 0; r < 256; ++r) a += src[r] * wcol[(size_t)r * HH];
    if (half) rbuf[j] = a;
    __syncthreads();
    if (!half) df_ws[b * HH + j] = ftanh(a + rbuf[j] + bs[j]);
}

__global__ __launch_bounds__(256) void epi_kernel(
    const float* __restrict__ e_ws, const float* __restrict__ mask,
    const float* __restrict__ is_ws,
    const float* __restrict__ c_hist, const float* __restrict__ h_hist,
    float* __restrict__ attns, float* __restrict__ cov,
    float* __restrict__ c_out, float* __restrict__ h_out)
{
    const int b = blockIdx.x;
    const int j = threadIdx.x;
    const float iS = is_ws[b];
    const float* e_last = e_ws + (size_t)((T_STEPS - 1) & 1) * BB * LL;
    for (int i = 0; i < LL / 256; ++i) {
        const int l = i * 256 + j;
        const int idx = b * LL + l;
        const float a = fexp(e_last[idx]) * mask[idx] * iS;
        attns[((size_t)(T_STEPS - 1) * BB + b) * LL + l] = a;
        cov[idx] += a;
    }
    c_out[b * HH + j] = c_hist[((size_t)(T_STEPS - 1) * BB + b) * HH + j];
    h_out[b * HH + j] = h_hist[((size_t)(T_STEPS - 1) * BB + b) * HH + j];
}

__global__ __launch_bounds__(512) void out_kernel(
    const float* __restrict__ h_hist, const float* __restrict__ ctx_hist,
    const float* __restrict__ c_hist, const float* __restrict__ x_hist,
    const float* __restrict__ Wo, const float* __restrict__ bo,
    const float* __restrict__ Wp, const float* __restrict__ bp,
    float* __restrict__ outs, float* __restrict__ pgens)
{
    const int t = blockIdx.x >> 2;
    const int bq = blockIdx.x & 3;
    const int tid = threadIdx.x;
    __shared__ float hs[16 * 256], cts[16 * 256], cs2[16 * 256], xs[16 * 128];
    __shared__ float zbuf[16 * 256];

    for (int i = tid; i < 16 * 256; i += 512) {
        const int bl = i >> 8, j = i & 255;
        const size_t row = ((size_t)t * BB + bq * 16 + bl) * HH;
        hs[i] = h_hist[row + j];
        cts[i] = ctx_hist[row + j];
        cs2[i] = c_hist[row + j];
    }
    for (int i = tid; i < 16 * 128; i += 512) {
        const int bl = i >> 7, j = i & 127;
        xs[i] = x_hist[((size_t)t * BB + bq * 16 + bl) * EE + j];
    }
    __syncthreads();

    {
        const int j = tid & 255, rh = tid >> 8;
        float acc[16];
        #pragma unroll
        for (int bl = 0; bl < 16; ++bl) acc[bl] = 0.f;
        const int r0 = rh * 128;
        #pragma unroll 4
        for (int r = r0; r < r0 + 128; ++r) {
            const float w0 = Wo[(size_t)r * HH + j];
            const float w1 = Wo[(size_t)(256 + r) * HH + j];
            #pragma unroll
            for (int bl = 0; bl < 16; ++bl)
                acc[bl] += hs[bl * 256 + r] * w0 + cts[bl * 256 + r] * w1;
        }
        if (rh) {
            #pragma unroll
            for (int bl = 0; bl < 16; ++bl) zbuf[bl * 256 + j] = acc[bl];
        }
        __syncthreads();
        if (!rh) {
            #pragma unroll
            for (int bl = 0; bl < 16; ++bl)
                outs[((size_t)t * BB + bq * 16 + bl) * HH + j] =
                    acc[bl] + zbuf[bl * 256 + j] + bo[j];
        }
    }

    {
        const int bl = tid >> 5, r32 = tid & 31;
        float pp = 0.f;
        for (int i = r32; i < 256; i += 32)
            pp += cts[bl * 256 + i] * Wp[i] + cs2[bl * 256 + i] * Wp[256 + i]
                + hs[bl * 256 + i] * Wp[512 + i];
        for (int i = r32; i < 128; i += 32)
            pp += xs[bl * 128 + i] * Wp[768 + i];
        pp += __shfl_xor(pp, 1);
        pp += __shfl_xor(pp, 2);
        pp += __shfl_xor(pp, 4);
        pp += __shfl_xor(pp, 8);
        pp += __shfl_xor(pp, 16);
        if (r32 == 0)
            pgens[(size_t)t * BB + bq * 16 + bl] = fsig(pp + bp[0]);
    }
}

extern "C" void kernel_launch(void* const* d_in, const int* in_sizes, int n_in,
                              void* d_out, int out_size, void* d_ws, size_t ws_size,
                              hipStream_t stream) {
    KParams p;
    p.dec_in = (const float*)d_in[0];
    p.init_c = (const float*)d_in[1];
    p.init_h = (const float*)d_in[2];
    p.enc    = (const float*)d_in[3];
    p.mask   = (const float*)d_in[4];
    p.Wx = (const float*)d_in[5];  p.bx = (const float*)d_in[6];
    p.Wl = (const float*)d_in[7];  p.bl = (const float*)d_in[8];
    p.Ws = (const float*)d_in[9];  p.bs = (const float*)d_in[10];
    p.v  = (const float*)d_in[11]; p.wc = (const float*)d_in[12];
    p.Wp = (const float*)d_in[13]; p.bp = (const float*)d_in[14];
    p.Wo = (const float*)d_in[15]; p.bo = (const float*)d_in[16];

    float* out = (float*)d_out;
    p.outs  = out;
    p.c_out = p.outs + (size_t)T_STEPS * BB * HH;
    p.h_out = p.c_out + BB * HH;
    p.attns = p.h_out + BB * HH;
    p.pgens = p.attns + (size_t)T_STEPS * BB * LL;
    p.cov   = p.pgens + T_STEPS * BB;

    float* ws = (float*)d_ws;
    p.encb = (uint4*)ws;
    float* w = ws + (size_t)BB * LL * HH / 2;
    p.e_ws = w;       w += 2 * BB * LL;
    float* sp = w;    w += NCHUNK * BB;            // fallback partials
    float* ctxp = w;  w += (size_t)NCHUNK * BB * HH;
    p.x_hist = w;     w += (size_t)T_STEPS * BB * EE;
    p.df_ws = w;      w += BB * HH;
    p.is_ws = w;      w += BB;
    p.ctx_hist = w;   w += (size_t)T_STEPS * BB * HH;
    p.c_hist = w;     w += (size_t)T_STEPS * BB * HH;
    p.h_hist = w;     w += (size_t)T_STEPS * BB * HH;
    p.ctx_acc = w;    w += BB * HH;                // coop accumulators
    p.S_acc = w;      w += BB;

    // ---- capture-safe, stateless cooperative-launch feasibility check ----
    int dev = 0;
    hipGetDevice(&dev);
    int numCU = 0;
    hipDeviceGetAttribute(&numCU, hipDeviceAttributeMultiprocessorCount, dev);
    int maxBlk = 0;
    hipError_t occ = hipOccupancyMaxActiveBlocksPerMultiprocessor(&maxBlk, mega_kernel, NTHR, 0);

    if (occ == hipSuccess && numCU > 0 && (long)maxBlk * numCU >= NBLK) {
        void* args[] = { &p };
        if (hipLaunchCooperativeKernel(mega_kernel, dim3(NBLK), dim3(NTHR),
                                       args, 0, stream) == hipSuccess)
            return;
    }

    // ---- fallback: proven r7 multi-kernel path ----
    conv_kernel<<<4096, 256, 0, stream>>>((const float4*)p.enc, p.encb);
    for (int t = 0; t < T_STEPS; ++t) {
        ctx_x_kernel<<<BB, 256, 0, stream>>>(p.dec_in, sp, ctxp, p.Wx, p.bx,
            p.ctx_hist, p.x_hist, p.is_ws, t);
        lstm_kernel<<<512, 128, 0, stream>>>(p.x_hist, p.init_c, p.init_h,
            p.Wl, p.bl, p.c_hist, p.h_hist, t);
        df_kernel<<<BB, 512, 0, stream>>>(p.c_hist, p.h_hist, p.Ws, p.bs,
            p.df_ws, t);
        attn_kernel<<<NCHUNK * BB, 256, 0, stream>>>(p.encb, p.mask, p.cov,
            p.df_ws, p.v, p.wc, p.e_ws, p.attns, p.is_ws, sp, ctxp, t);
    }
    ctx_x_kernel<<<BB, 256, 0, stream>>>(p.dec_in, sp, ctxp, p.Wx, p.bx,
        p.ctx_hist, p.x_hist, p.is_ws, T_STEPS);
    epi_kernel<<<BB, 256, 0, stream>>>(p.e_ws, p.mask, p.is_ws,
        p.c_hist, p.h_hist, p.attns, p.cov, p.c_out, p.h_out);
    out_kernel<<<256, 512, 0, stream>>>(p.h_hist, p.ctx_hist, p.c_hist,
        p.x_hist, p.Wo, p.bo, p.Wp, p.bp, p.outs, p.pgens);
}